// Round 8
// baseline (235.369 us; speedup 1.0000x reference)
//
#include <hip/hip_runtime.h>
#include <math.h>

#define N 128
#define HID 512
#define NH (N * HID)                 // 65536
#define SNH ((size_t)N * NH)         // 8388608 elements per s
#define NPAIRS (N * (N + 1) / 2)     // 8256
#define REP 4                        // instrumentation: idempotent repeats

// workspace layout (float offsets)
#define OFF_SA 0                     // Sa [2][128][512]
#define OFF_SB 131072                // Sb [2][128][512]
#define OFF_DG 262144                // Dg [2][128][512]
#define OFF_SV 393216                // Sv [2][512]
#define OFF_DB 394240                // Db [2][512]

typedef float vf4 __attribute__((ext_vector_type(4)));
union F4 { vf4 v; float f[4]; };

// ---------------------------------------------------------------------------
// K1: one block per (s, idx, pass). 512 blocks x 512 threads.
//   pass 0: Sa[s][idx][h] = sum_a x[s][a][idx][h]
//   pass 1: Sb[s][idx][h] = sum_b x[s][idx][b][h], Dg[s][idx][h] = x[s][idx][idx][h]
// ---------------------------------------------------------------------------
__global__ __launch_bounds__(512, 4)
void schur_p1(const float* __restrict__ x,
              float* __restrict__ Sa, float* __restrict__ Sb,
              float* __restrict__ Dg) {
    const int u    = blockIdx.x;
    const int pass = u & 1;
    const int idx  = (u >> 1) & 127;
    const int s    = u >> 8;
    const int tid  = threadIdx.x;
    const int hg   = tid & 127;
    const int q    = tid >> 7;            // 0..3
    const int hoff = hg * 4;

    const float* xs = x + (size_t)s * SNH;
    __shared__ F4 red[4][128];            // 8 KiB

    for (int rep = 0; rep < REP; ++rep) {
        F4 a0, a1, a2, a3;
        a0.v = (vf4)(0.f); a1.v = (vf4)(0.f); a2.v = (vf4)(0.f); a3.v = (vf4)(0.f);
        F4 dv; dv.v = (vf4)(0.f);

        if (pass == 0) {
            const float* p = xs + (size_t)(q * 32) * NH + idx * HID + hoff;
            for (int a = 0; a < 32; a += 4) {
                F4 v0; v0.v = *reinterpret_cast<const vf4*>(p + (size_t)(a + 0) * NH);
                F4 v1; v1.v = *reinterpret_cast<const vf4*>(p + (size_t)(a + 1) * NH);
                F4 v2; v2.v = *reinterpret_cast<const vf4*>(p + (size_t)(a + 2) * NH);
                F4 v3; v3.v = *reinterpret_cast<const vf4*>(p + (size_t)(a + 3) * NH);
                a0.v += v0.v; a1.v += v1.v; a2.v += v2.v; a3.v += v3.v;
            }
        } else {
            const float* p = xs + (size_t)idx * NH + (q * 32) * HID + hoff;
            for (int b = 0; b < 32; b += 4) {
                F4 v0; v0.v = *reinterpret_cast<const vf4*>(p + (b + 0) * HID);
                F4 v1; v1.v = *reinterpret_cast<const vf4*>(p + (b + 1) * HID);
                F4 v2; v2.v = *reinterpret_cast<const vf4*>(p + (b + 2) * HID);
                F4 v3; v3.v = *reinterpret_cast<const vf4*>(p + (b + 3) * HID);
                a0.v += v0.v; a1.v += v1.v; a2.v += v2.v; a3.v += v3.v;
            }
            if (q == 0)
                dv.v = *reinterpret_cast<const vf4*>(xs + (size_t)idx * NH + idx * HID + hoff);
        }
        a0.v = (a0.v + a1.v) + (a2.v + a3.v);
        red[q][hg] = a0;
        __syncthreads();

        if (q == 0) {
            F4 t;
            t.v = (red[0][hg].v + red[1][hg].v) + (red[2][hg].v + red[3][hg].v);
            float* dst = (pass == 0 ? Sa : Sb) + ((size_t)s * N + idx) * HID + hoff;
            *reinterpret_cast<vf4*>(dst) = t.v;
            if (pass == 1)
                *reinterpret_cast<vf4*>(Dg + ((size_t)s * N + idx) * HID + hoff) = dv.v;
        }
        __syncthreads();
    }
}

// ---------------------------------------------------------------------------
// K2 (mini): T = sum_i Sb_i, D = sum_i Dg_i -> Sv = (T-D)/(n(n-1)), Db = D/n.
// 8 blocks x 512 threads: block = (s, 128-h chunk); thread = (iq[0..3], hl[0..127]).
// ---------------------------------------------------------------------------
__global__ __launch_bounds__(512)
void schur_p2(const float* __restrict__ Sb, const float* __restrict__ Dg,
              float* __restrict__ Sv, float* __restrict__ Db) {
    const int bi  = blockIdx.x;           // 0..7
    const int s   = bi >> 2;
    const int hc  = bi & 3;
    const int tid = threadIdx.x;
    const int iq  = tid >> 7;             // 0..3
    const int hl  = tid & 127;
    const int h   = hc * 128 + hl;
    const size_t base = (size_t)s * N * HID;

    __shared__ float redT[4][128];
    __shared__ float redD[4][128];

    for (int rep = 0; rep < REP; ++rep) {
        float T = 0.f, D = 0.f;
        #pragma unroll
        for (int i = iq; i < N; i += 4) {
            T += Sb[base + (size_t)i * HID + h];
            D += Dg[base + (size_t)i * HID + h];
        }
        redT[iq][hl] = T;
        redD[iq][hl] = D;
        __syncthreads();
        if (iq == 0) {
            const float Tt = redT[0][hl] + redT[1][hl] + redT[2][hl] + redT[3][hl];
            const float Dd = redD[0][hl] + redD[1][hl] + redD[2][hl] + redD[3][hl];
            Sv[s * HID + h] = (Tt - Dd) * (1.0f / 16256.0f);
            Db[s * HID + h] = Dd * (1.0f / 128.0f);
        }
        __syncthreads();
    }
}

// ---------------------------------------------------------------------------
// K3: output over triangular pairs; xr/yc computed inline from Sa/Sb/Dg/Sv.
// 2064 blocks x 256 threads, 8 consecutive pairs per block; NT stores.
// ---------------------------------------------------------------------------
__global__ __launch_bounds__(256)
void schur_p3(const float* __restrict__ x, const float* __restrict__ w,
              const float* __restrict__ iso,
              const float* __restrict__ Sa, const float* __restrict__ Sb,
              const float* __restrict__ Dg,
              const float* __restrict__ Sv, const float* __restrict__ Db,
              float* __restrict__ out) {
    const int t  = threadIdx.x;
    const int k  = t >> 7;                // pair slot 0/1
    const int ht = t & 127;
    const int hoff = ht * 4;

    float c[7];
    #pragma unroll
    for (int j = 0; j < 7; ++j) {
        float acc = 0.f;
        #pragma unroll
        for (int i = 0; i < 7; ++i) acc += w[i * 7 + j] * iso[i * 7 + j];
        c[j] = acc;
    }
    const float c1 = c[0], c2 = c[1], c3 = c[2], c4 = c[3], c5 = c[4];
    const float al = 0.5f * (c[5] + c[6]);
    const float be = 0.5f * (c[5] - c[6]);
    const float inv = 1.0f / 16128.0f;    // 1/(n(n-2))

    const int pg0 = blockIdx.x * 8;

    #define TRI_OFF(aa) ((aa) * N - (((aa) * ((aa) - 1)) >> 1))
    for (int rep = 0; rep < REP; ++rep) {
        #pragma unroll
        for (int it = 0; it < 4; ++it) {
            const int pg = pg0 + it * 2 + k;      // global pair id, < 16512
            const int s  = (pg >= NPAIRS) ? 1 : 0;
            const int p  = pg - s * NPAIRS;

            int a = (int)((257.0f - sqrtf((float)(66049 - 8 * p))) * 0.5f);
            if (a < 0) a = 0;
            if (a > N - 1) a = N - 1;
            while (a > 0 && TRI_OFF(a) > p) --a;
            while (TRI_OFF(a + 1) <= p) ++a;
            const int b = a + (p - TRI_OFF(a));

            const size_t sbase    = (size_t)s * SNH;
            const size_t statbase = (size_t)s * N * HID;

            if (a == b) {
                F4 v;  v.v  = *reinterpret_cast<const vf4*>(x + sbase + ((size_t)a * N + a) * HID + hoff);
                F4 db; db.v = *reinterpret_cast<const vf4*>(Db + (size_t)s * HID + hoff);
                F4 o;
                #pragma unroll
                for (int j = 0; j < 4; ++j)
                    o.f[j] = c1 * db.f[j] + c2 * (v.f[j] - db.f[j]);
                __builtin_nontemporal_store(o.v,
                    reinterpret_cast<vf4*>(out + sbase + ((size_t)a * N + a) * HID + hoff));
                continue;
            }

            F4 va;  va.v  = *reinterpret_cast<const vf4*>(x + sbase + ((size_t)a * N + b) * HID + hoff);
            F4 vb;  vb.v  = *reinterpret_cast<const vf4*>(x + sbase + ((size_t)b * N + a) * HID + hoff);
            F4 saa; saa.v = *reinterpret_cast<const vf4*>(Sa + statbase + (size_t)a * HID + hoff);
            F4 sba; sba.v = *reinterpret_cast<const vf4*>(Sb + statbase + (size_t)a * HID + hoff);
            F4 dga; dga.v = *reinterpret_cast<const vf4*>(Dg + statbase + (size_t)a * HID + hoff);
            F4 sab; sab.v = *reinterpret_cast<const vf4*>(Sa + statbase + (size_t)b * HID + hoff);
            F4 sbb; sbb.v = *reinterpret_cast<const vf4*>(Sb + statbase + (size_t)b * HID + hoff);
            F4 dgb; dgb.v = *reinterpret_cast<const vf4*>(Dg + statbase + (size_t)b * HID + hoff);
            F4 sh;  sh.v  = *reinterpret_cast<const vf4*>(Sv + (size_t)s * HID + hoff);

            F4 oab, oba;
            #pragma unroll
            for (int j = 0; j < 4; ++j) {
                const float shj   = sh.f[j];
                const float k127s = 127.0f * shj;
                const float ra = saa.f[j] - dga.f[j] - k127s;
                const float ca = sba.f[j] - dga.f[j] - k127s;
                const float rb = sab.f[j] - dgb.f[j] - k127s;
                const float cb = sbb.f[j] - dgb.f[j] - k127s;
                const float xra = (127.0f * ra + ca) * inv;
                const float yca = (127.0f * ca + ra) * inv;
                const float xrb = (127.0f * rb + cb) * inv;
                const float ycb = (127.0f * cb + rb) * inv;
                const float U = va.f[j] - shj - xrb - yca;
                const float V = vb.f[j] - shj - xra - ycb;
                oab.f[j] = c3 * shj + c4 * xrb + c5 * yca + al * U + be * V;
                oba.f[j] = c3 * shj + c4 * xra + c5 * ycb + al * V + be * U;
            }
            __builtin_nontemporal_store(oab.v,
                reinterpret_cast<vf4*>(out + sbase + ((size_t)a * N + b) * HID + hoff));
            __builtin_nontemporal_store(oba.v,
                reinterpret_cast<vf4*>(out + sbase + ((size_t)b * N + a) * HID + hoff));
        }
    }
}

extern "C" void kernel_launch(void* const* d_in, const int* in_sizes, int n_in,
                              void* d_out, int out_size, void* d_ws, size_t ws_size,
                              hipStream_t stream) {
    const float* x   = (const float*)d_in[0];
    const float* w   = (const float*)d_in[1];
    const float* iso = (const float*)d_in[2];
    float* out = (float*)d_out;
    float* ws  = (float*)d_ws;

    float* Sa = ws + OFF_SA;
    float* Sb = ws + OFF_SB;
    float* Dg = ws + OFF_DG;
    float* Sv = ws + OFF_SV;
    float* Db = ws + OFF_DB;

    schur_p1<<<512, 512, 0, stream>>>(x, Sa, Sb, Dg);
    schur_p2<<<8, 512, 0, stream>>>(Sb, Dg, Sv, Db);
    schur_p3<<<2064, 256, 0, stream>>>(x, w, iso, Sa, Sb, Dg, Sv, Db, out);
}

// Round 10
// 59.700 us; speedup vs baseline: 3.9425x; 3.9425x over previous
//
#include <hip/hip_runtime.h>
#include <math.h>

#define N 128
#define HID 512
#define NH (N * HID)                 // 65536
#define SNH ((size_t)N * NH)         // 8388608 elements per s
#define NPAIRS (N * (N + 1) / 2)     // 8256

// workspace layout (float offsets)
#define OFF_SA 0                     // Sa [2][128][512]
#define OFF_SB 131072                // Sb [2][128][512]
#define OFF_DG 262144                // Dg [2][128][512]
#define OFF_SV 393216                // Sv [2][512]
#define OFF_DB 394240                // Db [2][512]

typedef float vf4 __attribute__((ext_vector_type(4)));
union F4 { vf4 v; float f[4]; };

// ---------------------------------------------------------------------------
// K1: 2048 blocks x 256 threads = 8 blocks/CU, 32 waves/CU (full occupancy).
// Block = (s, idx, pass, h-quarter): 2*128*2*4 = 2048 EXACTLY (decode checked).
// Threads = 32 hg x 8 q; q sums 16 indices, 4-way unrolled; block owns 128 h.
//   pass 0: Sa[s][idx][h] = sum_a x[s][a][idx][h]
//   pass 1: Sb[s][idx][h] = sum_b x[s][idx][b][h], Dg[s][idx][h] = x[s][idx][idx][h]
// ---------------------------------------------------------------------------
__global__ __launch_bounds__(256, 8)
void schur_p1(const float* __restrict__ x,
              float* __restrict__ Sa, float* __restrict__ Sb,
              float* __restrict__ Dg) {
    const int u    = blockIdx.x;          // 0..2047
    const int pass = u & 1;
    const int qt   = (u >> 1) & 3;        // h-quarter
    const int idx  = (u >> 3) & 127;
    const int s    = u >> 10;             // 0..1
    const int tid  = threadIdx.x;         // 0..255
    const int hg   = tid & 31;
    const int q    = tid >> 5;            // 0..7
    const int hoff = qt * 128 + hg * 4;   // float offset within [0,512)

    const float* xs = x + (size_t)s * SNH;
    __shared__ F4 red[8][32];             // 4 KiB

    F4 a0, a1, a2, a3;
    a0.v = (vf4)(0.f); a1.v = (vf4)(0.f); a2.v = (vf4)(0.f); a3.v = (vf4)(0.f);
    F4 dv; dv.v = (vf4)(0.f);

    if (pass == 0) {
        const float* p = xs + (size_t)(q * 16) * NH + idx * HID + hoff;
        #pragma unroll
        for (int a = 0; a < 16; a += 4) {
            F4 v0; v0.v = *reinterpret_cast<const vf4*>(p + (size_t)(a + 0) * NH);
            F4 v1; v1.v = *reinterpret_cast<const vf4*>(p + (size_t)(a + 1) * NH);
            F4 v2; v2.v = *reinterpret_cast<const vf4*>(p + (size_t)(a + 2) * NH);
            F4 v3; v3.v = *reinterpret_cast<const vf4*>(p + (size_t)(a + 3) * NH);
            a0.v += v0.v; a1.v += v1.v; a2.v += v2.v; a3.v += v3.v;
        }
    } else {
        const float* p = xs + (size_t)idx * NH + (q * 16) * HID + hoff;
        #pragma unroll
        for (int b = 0; b < 16; b += 4) {
            F4 v0; v0.v = *reinterpret_cast<const vf4*>(p + (b + 0) * HID);
            F4 v1; v1.v = *reinterpret_cast<const vf4*>(p + (b + 1) * HID);
            F4 v2; v2.v = *reinterpret_cast<const vf4*>(p + (b + 2) * HID);
            F4 v3; v3.v = *reinterpret_cast<const vf4*>(p + (b + 3) * HID);
            a0.v += v0.v; a1.v += v1.v; a2.v += v2.v; a3.v += v3.v;
        }
        if (q == 0)
            dv.v = *reinterpret_cast<const vf4*>(xs + (size_t)idx * NH + idx * HID + hoff);
    }
    a0.v = (a0.v + a1.v) + (a2.v + a3.v);
    red[q][hg] = a0;
    __syncthreads();

    if (q == 0) {
        F4 t;
        t.v = ((red[0][hg].v + red[1][hg].v) + (red[2][hg].v + red[3][hg].v))
            + ((red[4][hg].v + red[5][hg].v) + (red[6][hg].v + red[7][hg].v));
        float* dst = (pass == 0 ? Sa : Sb) + ((size_t)s * N + idx) * HID + hoff;
        *reinterpret_cast<vf4*>(dst) = t.v;
        if (pass == 1)
            *reinterpret_cast<vf4*>(Dg + ((size_t)s * N + idx) * HID + hoff) = dv.v;
    }
}

// ---------------------------------------------------------------------------
// K2 (mini): T = sum_i Sb_i, D = sum_i Dg_i -> Sv = (T-D)/(n(n-1)), Db = D/n.
// 8 blocks x 512 threads.  (unchanged from R8, passing)
// ---------------------------------------------------------------------------
__global__ __launch_bounds__(512)
void schur_p2(const float* __restrict__ Sb, const float* __restrict__ Dg,
              float* __restrict__ Sv, float* __restrict__ Db) {
    const int bi  = blockIdx.x;           // 0..7
    const int s   = bi >> 2;
    const int hc  = bi & 3;
    const int tid = threadIdx.x;
    const int iq  = tid >> 7;             // 0..3
    const int hl  = tid & 127;
    const int h   = hc * 128 + hl;
    const size_t base = (size_t)s * N * HID;

    __shared__ float redT[4][128];
    __shared__ float redD[4][128];

    float T = 0.f, D = 0.f;
    #pragma unroll
    for (int i = iq; i < N; i += 4) {
        T += Sb[base + (size_t)i * HID + h];
        D += Dg[base + (size_t)i * HID + h];
    }
    redT[iq][hl] = T;
    redD[iq][hl] = D;
    __syncthreads();
    if (iq == 0) {
        const float Tt = redT[0][hl] + redT[1][hl] + redT[2][hl] + redT[3][hl];
        const float Dd = redD[0][hl] + redD[1][hl] + redD[2][hl] + redD[3][hl];
        Sv[s * HID + h] = (Tt - Dd) * (1.0f / 16256.0f);
        Db[s * HID + h] = Dd * (1.0f / 128.0f);
    }
}

// ---------------------------------------------------------------------------
// K3: output over triangular pairs; xr/yc computed inline from Sa/Sb/Dg/Sv.
// 2064 blocks x 256 threads, 8 consecutive pairs per block; NT stores.
// (unchanged from R8, passing)
// ---------------------------------------------------------------------------
__global__ __launch_bounds__(256)
void schur_p3(const float* __restrict__ x, const float* __restrict__ w,
              const float* __restrict__ iso,
              const float* __restrict__ Sa, const float* __restrict__ Sb,
              const float* __restrict__ Dg,
              const float* __restrict__ Sv, const float* __restrict__ Db,
              float* __restrict__ out) {
    const int t  = threadIdx.x;
    const int k  = t >> 7;                // pair slot 0/1
    const int ht = t & 127;
    const int hoff = ht * 4;

    float c[7];
    #pragma unroll
    for (int j = 0; j < 7; ++j) {
        float acc = 0.f;
        #pragma unroll
        for (int i = 0; i < 7; ++i) acc += w[i * 7 + j] * iso[i * 7 + j];
        c[j] = acc;
    }
    const float c1 = c[0], c2 = c[1], c3 = c[2], c4 = c[3], c5 = c[4];
    const float al = 0.5f * (c[5] + c[6]);
    const float be = 0.5f * (c[5] - c[6]);
    const float inv = 1.0f / 16128.0f;    // 1/(n(n-2))

    const int pg0 = blockIdx.x * 8;

    #define TRI_OFF(aa) ((aa) * N - (((aa) * ((aa) - 1)) >> 1))
    #pragma unroll
    for (int it = 0; it < 4; ++it) {
        const int pg = pg0 + it * 2 + k;      // global pair id, < 16512
        const int s  = (pg >= NPAIRS) ? 1 : 0;
        const int p  = pg - s * NPAIRS;

        int a = (int)((257.0f - sqrtf((float)(66049 - 8 * p))) * 0.5f);
        if (a < 0) a = 0;
        if (a > N - 1) a = N - 1;
        while (a > 0 && TRI_OFF(a) > p) --a;
        while (TRI_OFF(a + 1) <= p) ++a;
        const int b = a + (p - TRI_OFF(a));

        const size_t sbase    = (size_t)s * SNH;
        const size_t statbase = (size_t)s * N * HID;

        if (a == b) {
            F4 v;  v.v  = *reinterpret_cast<const vf4*>(x + sbase + ((size_t)a * N + a) * HID + hoff);
            F4 db; db.v = *reinterpret_cast<const vf4*>(Db + (size_t)s * HID + hoff);
            F4 o;
            #pragma unroll
            for (int j = 0; j < 4; ++j)
                o.f[j] = c1 * db.f[j] + c2 * (v.f[j] - db.f[j]);
            __builtin_nontemporal_store(o.v,
                reinterpret_cast<vf4*>(out + sbase + ((size_t)a * N + a) * HID + hoff));
            continue;
        }

        F4 va;  va.v  = *reinterpret_cast<const vf4*>(x + sbase + ((size_t)a * N + b) * HID + hoff);
        F4 vb;  vb.v  = *reinterpret_cast<const vf4*>(x + sbase + ((size_t)b * N + a) * HID + hoff);
        F4 saa; saa.v = *reinterpret_cast<const vf4*>(Sa + statbase + (size_t)a * HID + hoff);
        F4 sba; sba.v = *reinterpret_cast<const vf4*>(Sb + statbase + (size_t)a * HID + hoff);
        F4 dga; dga.v = *reinterpret_cast<const vf4*>(Dg + statbase + (size_t)a * HID + hoff);
        F4 sab; sab.v = *reinterpret_cast<const vf4*>(Sa + statbase + (size_t)b * HID + hoff);
        F4 sbb; sbb.v = *reinterpret_cast<const vf4*>(Sb + statbase + (size_t)b * HID + hoff);
        F4 dgb; dgb.v = *reinterpret_cast<const vf4*>(Dg + statbase + (size_t)b * HID + hoff);
        F4 sh;  sh.v  = *reinterpret_cast<const vf4*>(Sv + (size_t)s * HID + hoff);

        F4 oab, oba;
        #pragma unroll
        for (int j = 0; j < 4; ++j) {
            const float shj   = sh.f[j];
            const float k127s = 127.0f * shj;
            const float ra = saa.f[j] - dga.f[j] - k127s;
            const float ca = sba.f[j] - dga.f[j] - k127s;
            const float rb = sab.f[j] - dgb.f[j] - k127s;
            const float cb = sbb.f[j] - dgb.f[j] - k127s;
            const float xra = (127.0f * ra + ca) * inv;
            const float yca = (127.0f * ca + ra) * inv;
            const float xrb = (127.0f * rb + cb) * inv;
            const float ycb = (127.0f * cb + rb) * inv;
            const float U = va.f[j] - shj - xrb - yca;
            const float V = vb.f[j] - shj - xra - ycb;
            oab.f[j] = c3 * shj + c4 * xrb + c5 * yca + al * U + be * V;
            oba.f[j] = c3 * shj + c4 * xra + c5 * ycb + al * V + be * U;
        }
        __builtin_nontemporal_store(oab.v,
            reinterpret_cast<vf4*>(out + sbase + ((size_t)a * N + b) * HID + hoff));
        __builtin_nontemporal_store(oba.v,
            reinterpret_cast<vf4*>(out + sbase + ((size_t)b * N + a) * HID + hoff));
    }
}

extern "C" void kernel_launch(void* const* d_in, const int* in_sizes, int n_in,
                              void* d_out, int out_size, void* d_ws, size_t ws_size,
                              hipStream_t stream) {
    const float* x   = (const float*)d_in[0];
    const float* w   = (const float*)d_in[1];
    const float* iso = (const float*)d_in[2];
    float* out = (float*)d_out;
    float* ws  = (float*)d_ws;

    float* Sa = ws + OFF_SA;
    float* Sb = ws + OFF_SB;
    float* Dg = ws + OFF_DG;
    float* Sv = ws + OFF_SV;
    float* Db = ws + OFF_DB;

    schur_p1<<<2048, 256, 0, stream>>>(x, Sa, Sb, Dg);
    schur_p2<<<8, 512, 0, stream>>>(Sb, Dg, Sv, Db);
    schur_p3<<<2064, 256, 0, stream>>>(x, w, iso, Sa, Sb, Dg, Sv, Db, out);
}

// Round 11
// 45.779 us; speedup vs baseline: 5.1414x; 1.3041x over previous
//
#include <hip/hip_runtime.h>
#include <math.h>

#define N 128
#define HID 512
#define NH (N * HID)                 // 65536
#define SNH ((size_t)N * NH)         // 8388608 elements per s
#define NPAIRS (N * (N + 1) / 2)     // 8256

// workspace layout (float offsets)
#define OFF_PSC 0                    // PScol [2][8][128][512]  (fold over a-groups)
#define OFF_PSR 4194304              // PSrow [2][4][128][512]? -> [2][4][128][512]=524288
#define OFF_DG  4718592              // Dg    [2][128][512]
#define OFF_XR  4849664              // Xr    [2][128][512]
#define OFF_YC  4980736              // Yc    [2][128][512]
#define OFF_SV  5111808              // Sv    [2][512]
#define OFF_DB  5112832              // Db    [2][512]

typedef float vf4 __attribute__((ext_vector_type(4)));
union F4 { vf4 v; float f[4]; };

// ---------------------------------------------------------------------------
// K1: stride-free dense-cube partial sums.
// Block = (s, g=a-octet-of-16, bq=b-quarter, hq=h-quarter): 2*8*4*4 = 256.
// Block reads x[s][g*16..+16][bq*32..+32][hq*128..+128] = 256 KB, each line
// touched by exactly one block chip-wide (plus tiny diag re-reads).
//   PScol[s][g][b][h]  = sum_{a in g}  x[s][a][b][h]   (register acc)
//   PSrow[s][bq][a][h] = sum_{b in bq} x[s][a][b][h]   (LDS reduce)
//   Dg[s][a][h]        = x[s][a][a][h]
// 512 threads = f(32 float4 of h-quarter) x bg(16, 2 b's each).
// ---------------------------------------------------------------------------
__global__ __launch_bounds__(512)
void schur_p1(const float* __restrict__ x, float* __restrict__ PScol,
              float* __restrict__ PSrow, float* __restrict__ Dg) {
    const int u  = blockIdx.x;            // 0..255
    const int hq = u & 3;
    const int bq = (u >> 2) & 3;
    const int g  = (u >> 4) & 7;
    const int s  = u >> 7;                // 0..1
    const int tid = threadIdx.x;
    const int f   = tid & 31;             // float4 within h-quarter
    const int bg  = tid >> 5;             // 0..15, 2 b's each
    const int b0  = bq * 32 + bg * 2;
    const int hoff = hq * 128 + f * 4;

    const float* xs   = x + (size_t)s * SNH;
    const float* base = xs + (size_t)(g * 16) * NH + b0 * HID + hoff;

    __shared__ F4 rowred[8][16][32];      // 64 KiB (proven-OK static size, R5)

    F4 acc0, acc1;
    acc0.v = (vf4)(0.f); acc1.v = (vf4)(0.f);

    #pragma unroll
    for (int c = 0; c < 2; ++c) {
        #pragma unroll
        for (int al = 0; al < 8; ++al) {
            const float* p = base + (size_t)(c * 8 + al) * NH;
            F4 v0; v0.v = *reinterpret_cast<const vf4*>(p);
            F4 v1; v1.v = *reinterpret_cast<const vf4*>(p + HID);
            acc0.v += v0.v;
            acc1.v += v1.v;
            F4 rs; rs.v = v0.v + v1.v;
            rowred[al][bg][f] = rs;
        }
        __syncthreads();
        if (tid < 256) {
            const int ar = tid >> 5;      // 0..7
            const int f2 = tid & 31;
            F4 t; t.v = (vf4)(0.f);
            #pragma unroll
            for (int k = 0; k < 16; ++k) t.v += rowred[ar][k][f2].v;
            const int a = g * 16 + c * 8 + ar;
            *reinterpret_cast<vf4*>(PSrow +
                ((((size_t)s * 4 + bq) * N + a) * HID + hq * 128 + f2 * 4)) = t.v;
        }
        __syncthreads();
    }

    *reinterpret_cast<vf4*>(PScol +
        ((((size_t)s * 8 + g) * N + b0) * HID + hoff)) = acc0.v;
    *reinterpret_cast<vf4*>(PScol +
        ((((size_t)s * 8 + g) * N + b0 + 1) * HID + hoff)) = acc1.v;

    if (bq == (g >> 1)) {
        const int ar = tid >> 5;          // 0..15
        const int f2 = tid & 31;
        const int a  = g * 16 + ar;
        const vf4 dv = *reinterpret_cast<const vf4*>(
            xs + (size_t)a * NH + a * HID + hq * 128 + f2 * 4);
        *reinterpret_cast<vf4*>(Dg +
            (((size_t)s * N + a) * HID + hq * 128 + f2 * 4)) = dv;
    }
}

// ---------------------------------------------------------------------------
// K2: fold PScol(8)/PSrow(4)/Dg -> per-(s,h) stats -> Xr, Yc, Sv, Db.
// 32 blocks x 512 threads (R5 structure, passing).
// ---------------------------------------------------------------------------
__global__ __launch_bounds__(512)
void schur_p2(const float* __restrict__ PScol, const float* __restrict__ PSrow,
              const float* __restrict__ Dg,
              float* __restrict__ Xr, float* __restrict__ Yc,
              float* __restrict__ Sv, float* __restrict__ Db) {
    const int bi = blockIdx.x;            // 0..31
    const int s  = bi >> 4;
    const int hc = bi & 15;
    const int t  = threadIdx.x;
    const int iq = t >> 5;                // 0..15
    const int hl = t & 31;
    const int h  = hc * 32 + hl;

    float sa8[8], sb8[8], d8[8];
    float T = 0.f, D = 0.f;
    #pragma unroll
    for (int k = 0; k < 8; ++k) {
        const int i = iq + k * 16;
        float sa = 0.f, sb = 0.f;
        #pragma unroll
        for (int gg = 0; gg < 8; ++gg)
            sa += PScol[(((size_t)s * 8 + gg) * N + i) * HID + h];
        #pragma unroll
        for (int qq = 0; qq < 4; ++qq)
            sb += PSrow[(((size_t)s * 4 + qq) * N + i) * HID + h];
        const float d = Dg[((size_t)s * N + i) * HID + h];
        sa8[k] = sa; sb8[k] = sb; d8[k] = d;
        T += sa; D += d;
    }

    __shared__ float redT[16][32];
    __shared__ float redD[16][32];
    __shared__ float shS[32];
    redT[iq][hl] = T;
    redD[iq][hl] = D;
    __syncthreads();
    if (iq == 0) {
        float Tt = 0.f, Dd = 0.f;
        #pragma unroll
        for (int q = 0; q < 16; ++q) { Tt += redT[q][hl]; Dd += redD[q][hl]; }
        const float sh   = (Tt - Dd) * (1.0f / 16256.0f);   // /(n(n-1))
        const float dbar = Dd * (1.0f / 128.0f);
        Sv[s * HID + h] = sh;
        Db[s * HID + h] = dbar;
        shS[hl] = sh;
    }
    __syncthreads();

    const float sh    = shS[hl];
    const float k127s = 127.0f * sh;
    const float inv   = 1.0f / 16128.0f;  // 1/(n(n-2))
    const size_t base = (size_t)s * N * HID;
    #pragma unroll
    for (int k = 0; k < 8; ++k) {
        const int i = iq + k * 16;
        const float d = d8[k];
        const float r = sa8[k] - d - k127s;
        const float c = sb8[k] - d - k127s;
        Xr[base + (size_t)i * HID + h] = (127.0f * r + c) * inv;
        Yc[base + (size_t)i * HID + h] = (127.0f * c + r) * inv;
    }
}

// ---------------------------------------------------------------------------
// K3: output over triangular pairs (R5 p3, verbatim; passing, ~near-BW).
// 2064 blocks x 256 threads, 8 consecutive pairs per block; NT stores.
// ---------------------------------------------------------------------------
__global__ __launch_bounds__(256)
void schur_p3(const float* __restrict__ x, const float* __restrict__ w,
              const float* __restrict__ iso,
              const float* __restrict__ Xr, const float* __restrict__ Yc,
              const float* __restrict__ Sv, const float* __restrict__ Db,
              float* __restrict__ out) {
    const int t  = threadIdx.x;
    const int k  = t >> 7;                // pair slot 0/1
    const int ht = t & 127;
    const int hoff = ht * 4;

    float c[7];
    #pragma unroll
    for (int j = 0; j < 7; ++j) {
        float acc = 0.f;
        #pragma unroll
        for (int i = 0; i < 7; ++i) acc += w[i * 7 + j] * iso[i * 7 + j];
        c[j] = acc;
    }
    const float c1 = c[0], c2 = c[1], c3 = c[2], c4 = c[3], c5 = c[4];
    const float al = 0.5f * (c[5] + c[6]);
    const float be = 0.5f * (c[5] - c[6]);

    const int pg0 = blockIdx.x * 8;

    #define TRI_OFF(aa) ((aa) * N - (((aa) * ((aa) - 1)) >> 1))
    #pragma unroll
    for (int it = 0; it < 4; ++it) {
        const int pg = pg0 + it * 2 + k;      // global pair id, < 16512
        const int s  = (pg >= NPAIRS) ? 1 : 0;
        const int p  = pg - s * NPAIRS;

        int a = (int)((257.0f - sqrtf((float)(66049 - 8 * p))) * 0.5f);
        if (a < 0) a = 0;
        if (a > N - 1) a = N - 1;
        while (a > 0 && TRI_OFF(a) > p) --a;
        while (TRI_OFF(a + 1) <= p) ++a;
        const int b = a + (p - TRI_OFF(a));

        const size_t sbase    = (size_t)s * SNH;
        const size_t statbase = (size_t)s * N * HID;

        if (a == b) {
            F4 v;  v.v  = *reinterpret_cast<const vf4*>(x + sbase + ((size_t)a * N + a) * HID + hoff);
            F4 db; db.v = *reinterpret_cast<const vf4*>(Db + (size_t)s * HID + hoff);
            F4 o;
            #pragma unroll
            for (int j = 0; j < 4; ++j)
                o.f[j] = c1 * db.f[j] + c2 * (v.f[j] - db.f[j]);
            __builtin_nontemporal_store(o.v,
                reinterpret_cast<vf4*>(out + sbase + ((size_t)a * N + a) * HID + hoff));
            continue;
        }

        F4 va;  va.v  = *reinterpret_cast<const vf4*>(x + sbase + ((size_t)a * N + b) * HID + hoff);
        F4 vb;  vb.v  = *reinterpret_cast<const vf4*>(x + sbase + ((size_t)b * N + a) * HID + hoff);
        F4 xra; xra.v = *reinterpret_cast<const vf4*>(Xr + statbase + (size_t)a * HID + hoff);
        F4 xrb; xrb.v = *reinterpret_cast<const vf4*>(Xr + statbase + (size_t)b * HID + hoff);
        F4 yca; yca.v = *reinterpret_cast<const vf4*>(Yc + statbase + (size_t)a * HID + hoff);
        F4 ycb; ycb.v = *reinterpret_cast<const vf4*>(Yc + statbase + (size_t)b * HID + hoff);
        F4 sh;  sh.v  = *reinterpret_cast<const vf4*>(Sv + (size_t)s * HID + hoff);

        F4 oab, oba;
        #pragma unroll
        for (int j = 0; j < 4; ++j) {
            const float U = va.f[j] - sh.f[j] - xrb.f[j] - yca.f[j];
            const float V = vb.f[j] - sh.f[j] - xra.f[j] - ycb.f[j];
            oab.f[j] = c3 * sh.f[j] + c4 * xrb.f[j] + c5 * yca.f[j] + al * U + be * V;
            oba.f[j] = c3 * sh.f[j] + c4 * xra.f[j] + c5 * ycb.f[j] + al * V + be * U;
        }
        __builtin_nontemporal_store(oab.v,
            reinterpret_cast<vf4*>(out + sbase + ((size_t)a * N + b) * HID + hoff));
        __builtin_nontemporal_store(oba.v,
            reinterpret_cast<vf4*>(out + sbase + ((size_t)b * N + a) * HID + hoff));
    }
}

extern "C" void kernel_launch(void* const* d_in, const int* in_sizes, int n_in,
                              void* d_out, int out_size, void* d_ws, size_t ws_size,
                              hipStream_t stream) {
    const float* x   = (const float*)d_in[0];
    const float* w   = (const float*)d_in[1];
    const float* iso = (const float*)d_in[2];
    float* out = (float*)d_out;
    float* ws  = (float*)d_ws;

    float* PScol = ws + OFF_PSC;
    float* PSrow = ws + OFF_PSR;
    float* Dg    = ws + OFF_DG;
    float* Xr    = ws + OFF_XR;
    float* Yc    = ws + OFF_YC;
    float* Sv    = ws + OFF_SV;
    float* Db    = ws + OFF_DB;

    schur_p1<<<256, 512, 0, stream>>>(x, PScol, PSrow, Dg);
    schur_p2<<<32, 512, 0, stream>>>(PScol, PSrow, Dg, Xr, Yc, Sv, Db);
    schur_p3<<<2064, 256, 0, stream>>>(x, w, iso, Xr, Yc, Sv, Db, out);
}